// Round 8
// baseline (229.615 us; speedup 1.0000x reference)
//
#include <hip/hip_runtime.h>
#include <hip/hip_bf16.h>

#define NN 16384

typedef __attribute__((ext_vector_type(4))) float  f32x4;
typedef __attribute__((ext_vector_type(8))) short  s16x8;
typedef __attribute__((ext_vector_type(4))) short  s16x4;

__device__ inline short bf16_of(float f) {
    return __builtin_bit_cast(short, __float2bfloat16(f));
}

// Kernel 1: HpT[c][m] (bf16), c = b*16+g.  h[b,m,g] = sum_f x[b,m,f]*ker[m,f,g]
__global__ void fuse_h(const float* __restrict__ x, const float* __restrict__ ker,
                       __hip_bfloat16* __restrict__ hpt) {
    int tid = blockIdx.x * 256 + threadIdx.x;
    int g = tid & 15;
    int m = tid >> 4;            // 0..16383
    const float* xb0 = x + m * 16;
    const float* xb1 = x + NN * 16 + m * 16;
    const float* kp  = ker + m * 256 + g;
    float h0 = 0.f, h1 = 0.f;
#pragma unroll
    for (int f = 0; f < 16; ++f) {
        float kk = kp[f * 16];
        h0 += xb0[f] * kk;
        h1 += xb1[f] * kk;
    }
    hpt[g * NN + m]        = __float2bfloat16(h0);
    hpt[(16 + g) * NN + m] = __float2bfloat16(h1);
}

// Kernel 2: partial[ks][n][c] = sum_{m in ks-slice} A[n,m]*Hp[m,c]
// Grid 512 = 256 rowBlocks x 2 K-splits = exactly 2 blocks/CU resident.
// Block: 4 waves x 16 rows, zero barriers. K-step 512: each A row is read as
// TWO back-to-back 1KB loads = 2KB sequential per DRAM page visit (halves the
// page-activation rate vs R6's 1KB). Wave-private 16KB LDS tile, same XOR
// swizzle family (1024B rows), B-before-A issue order, single A-drain point
// per iteration (second B batch, right before the LDS write that needs it).
__global__ __launch_bounds__(256, 2) void gcn_partial(
        const float* __restrict__ A,
        const __hip_bfloat16* __restrict__ hpt,
        float* __restrict__ part) {
    __shared__ __attribute__((aligned(16))) char tile[4][16384];

    const int lane = threadIdx.x & 63;
    const int wave = threadIdx.x >> 6;   // 0..3
    const int rowBlk = blockIdx.x >> 1;
    const int ks     = blockIdx.x & 1;
    const int n0     = rowBlk * 64 + wave * 16;  // wave's 16 rows
    const int k0     = ks * 8192;

    // consume roles (MFMA fragment)
    const int row  = lane & 15;
    const int kg   = lane >> 4;

    char* lds = tile[wave];

    f32x4 acc0 = {0.f, 0.f, 0.f, 0.f};
    f32x4 acc1 = {0.f, 0.f, 0.f, 0.f};
    f32x4 st[32];                        // 16 rows x 2 bursts (2KB/row fp32)

    const float* abase = A + (size_t)n0 * NN + k0;
    const __hip_bfloat16* b0base = hpt + row * NN + k0 + kg * 8; // c-tile 0
    const __hip_bfloat16* b1base = b0base + 16 * NN;             // c-tile 1

    // ---- prologue: stage K-step 0 (16 rows x 2KB row-sequential bursts) ----
#pragma unroll
    for (int r = 0; r < 16; ++r) {
        st[2 * r]     = __builtin_nontemporal_load(
                            (const f32x4*)(abase + (size_t)r * NN + lane * 4));
        st[2 * r + 1] = __builtin_nontemporal_load(
                            (const f32x4*)(abase + (size_t)r * NN + 256 + lane * 4));
    }
#pragma unroll
    for (int r = 0; r < 16; ++r)
#pragma unroll
        for (int c = 0; c < 2; ++c) {
            int byte = (r * 1024 + c * 512 + lane * 8) ^ ((r & 7) << 4);
            f32x4 sv = st[2 * r + c];
            s16x4 v;
            v[0] = bf16_of(sv[0]); v[1] = bf16_of(sv[1]);
            v[2] = bf16_of(sv[2]); v[3] = bf16_of(sv[3]);
            *(s16x4*)(lds + byte) = v;
        }

#pragma unroll 1
    for (int t = 0; t < 16; ++t) {
        const int koff = t * 512;
        // B batch 0 (j=0..7) FIRST: its counted vmcnt wait must not drain the
        // A prefetch issued below (vmcnt is in-order).
        s16x8 bb0[8], bb1[8];
#pragma unroll
        for (int j = 0; j < 8; ++j) {
            bb0[j] = *(const s16x8*)(b0base + koff + j * 32);
            bb1[j] = *(const s16x8*)(b1base + koff + j * 32);
        }
        // A prefetch for t+1 (guarded; 2KB sequential per row)
        if (t < 15) {
            const float* ap = abase + koff + 512 + lane * 4;
#pragma unroll
            for (int r = 0; r < 16; ++r) {
                st[2 * r]     = __builtin_nontemporal_load(
                                    (const f32x4*)(ap + (size_t)r * NN));
                st[2 * r + 1] = __builtin_nontemporal_load(
                                    (const f32x4*)(ap + (size_t)r * NN + 256));
            }
        }
        // consume j=0..7 of current tile (waits only on B batch 0)
#pragma unroll
        for (int j = 0; j < 8; ++j) {
            int byte = (row * 1024 + j * 64 + kg * 16) ^ ((row & 7) << 4);
            s16x8 af = *(const s16x8*)(lds + byte);
            acc0 = __builtin_amdgcn_mfma_f32_16x16x32_bf16(af, bb0[j], acc0, 0, 0, 0);
            acc1 = __builtin_amdgcn_mfma_f32_16x16x32_bf16(af, bb1[j], acc1, 0, 0, 0);
        }
        // B batch 1 (j=8..15): issued after A; consuming it drains A, which
        // the LDS write below needs anyway -- single stall point per iter.
#pragma unroll
        for (int j = 0; j < 8; ++j) {
            bb0[j] = *(const s16x8*)(b0base + koff + (8 + j) * 32);
            bb1[j] = *(const s16x8*)(b1base + koff + (8 + j) * 32);
        }
#pragma unroll
        for (int j = 0; j < 8; ++j) {
            int byte = (row * 1024 + (8 + j) * 64 + kg * 16) ^ ((row & 7) << 4);
            s16x8 af = *(const s16x8*)(lds + byte);
            acc0 = __builtin_amdgcn_mfma_f32_16x16x32_bf16(af, bb0[j], acc0, 0, 0, 0);
            acc1 = __builtin_amdgcn_mfma_f32_16x16x32_bf16(af, bb1[j], acc1, 0, 0, 0);
        }
        // convert + write next tile (A drained; wave-private, no barrier)
        if (t < 15) {
#pragma unroll
            for (int r = 0; r < 16; ++r)
#pragma unroll
                for (int c = 0; c < 2; ++c) {
                    int byte = (r * 1024 + c * 512 + lane * 8) ^ ((r & 7) << 4);
                    f32x4 sv = st[2 * r + c];
                    s16x4 v;
                    v[0] = bf16_of(sv[0]); v[1] = bf16_of(sv[1]);
                    v[2] = bf16_of(sv[2]); v[3] = bf16_of(sv[3]);
                    *(s16x4*)(lds + byte) = v;
                }
        }
    }

    // D mapping: col = lane&15 (B col), row = kg*4 + i (A row). Each wave owns
    // its 16 rows exclusively -> direct global store of the partial.
    float* pb = part + (size_t)ks * (NN * 32);
#pragma unroll
    for (int i = 0; i < 4; ++i) {
        int n = n0 + kg * 4 + i;
        pb[n * 32 + row]      = acc0[i];
        pb[n * 32 + 16 + row] = acc1[i];
    }
}

// Kernel 3: out[b,n,g] = sum_ks part[ks][n][c] + bias[n,g]
__global__ void gcn_reduce(const float* __restrict__ part,
                           const float* __restrict__ bias,
                           float* __restrict__ out) {
    int idx = blockIdx.x * 256 + threadIdx.x;   // over 16384*32
    int n = idx >> 5, c = idx & 31;
    int b = c >> 4, g = c & 15;
    float s = part[idx] + part[idx + NN * 32];
    out[(size_t)b * (NN * 16) + n * 16 + g] = s + bias[n * 16 + g];
}

extern "C" void kernel_launch(void* const* d_in, const int* in_sizes, int n_in,
                              void* d_out, int out_size, void* d_ws, size_t ws_size,
                              hipStream_t stream) {
    const float* x    = (const float*)d_in[0];
    const float* A    = (const float*)d_in[1];
    const float* ker  = (const float*)d_in[2];
    const float* bias = (const float*)d_in[3];
    float* out = (float*)d_out;
    __hip_bfloat16* hpt = (__hip_bfloat16*)d_ws;            // 1 MB
    float* part = (float*)((char*)d_ws + (1 << 20));        // 2*16384*32*4 = 4 MB

    fuse_h<<<dim3(NN * 16 / 256), dim3(256), 0, stream>>>(x, ker, hpt);
    gcn_partial<<<dim3(512), dim3(256), 0, stream>>>(A, hpt, part);
    gcn_reduce<<<dim3(NN * 32 / 256), dim3(256), 0, stream>>>(part, bias, out);
}